// Round 3
// baseline (1198.743 us; speedup 1.0000x reference)
//
#include <hip/hip_runtime.h>
#include <math.h>

// ---------------------------------------------------------------------------
// QuantumSuperpositionAttention  (B=1, N=1024, DIM=512, H=8, DH=64, k=102)
//
// Identities:
//  * phase MLP is dead code: |alpha * e^{i phi}|^2 == |alpha|^2
//  * cayley(M): A = 0.02*((Mre - Mre^T) + i(Mim + Mim^T));
//    W = (I-A)^{-1}(I+A) = 2(I+A)X - I,  X = inv(I - A^2), spec [1,5).
//  * inv: deg-4 minimax init (PS form) + 2 NS -> rho ~ 7e-8 < fp32 floor.
//  * GEMM CORE LESSONS:
//    - 2x4 microtile is LDS-pipe-bound: 24 LDS-cyc vs 16 CU-FMA-slots per
//      wave-k -> 67% VALU ceiling, observed 55% (R9..R16 plateau).
//    - 4x4 microtile balances LDS:VALU 1:1 but needs >=2 waves/SIMD;
//      at 1 wave/SIMD (R17, 256 blocks) it REGRESSED to ~95us/GEMM.
//    - R17 absmax EXACT match => 4x4 inner loop is bit-identical per
//      element to 2x4 (same ascending-k chain, same contraction).
//  * ACCURACY RULES (R7/R9): never change summation ORDER in the
//    Wq/Wk/Q/K/scores chain. W REALIZATION changes at fp32-floor scale are
//    safe (R6/R8/R12/R13: all exactly 1 bf16 ulp).
//  * D_OUT BOUNDS RULE (R10/R11): every d_out store bounds-checked.
//
// R18: get 4x4 core the TLP it needs.
//  * Phase-A: cgemm44<64> (64x64 tile, 256 thr) with SPLIT-K=2 ->
//    512 blocks = 2 blocks/CU = 2 waves/SIMD. Partials P0 (in the target
//    slot) + P1 (scratch); deterministic combine C = P0 + P1 + old epilogue
//    modes in a tiny elementwise kernel (W-realization change: safe class).
//  * QKV: cgemm44<32> (64x32 tile, 128 thr), grid (16,16,3) = 768 blocks =
//    3 blocks/CU, NO k-split (order-critical chain, bit-exact core swap).
//  * out-proj: unchanged 32x64 mode-5 kernel (bounded d_out stores).
// ---------------------------------------------------------------------------

#define PLANE   262144      // 512*512
#define CMAT    524288      // floats per complex 512x512 (2 MB)
#define PPLANE  524288      // 1024*512
#define CPROJ   1048576     // floats per complex 1024x512 (4 MB)
#define KTOP    102

#define R_FLOATS (28*CMAT)  // phase A: 24*CMAT buffers + 4*CMAT split-K P1
#define POOL_FLOATS (4*CMAT + 8192 + R_FLOATS)
__device__ __attribute__((aligned(256))) float g_pool[POOL_FLOATS];

// ---------------------------------------------------------------------------
// 4x4-microtile complex GEMM core. C-tile 64 x TN, threads = 4*TN.
// Always plain C = A*B over k in [kbeg, kbeg+klen); split=1 encodes
// blockIdx.z = w*2 + khalf (khalf0 -> C0, khalf1 -> P1). No epilogue modes.
// ---------------------------------------------------------------------------
template<int TN>
__launch_bounds__(TN*4)
__global__ void cgemm44_kernel(
    const float* __restrict__ Are, const float* __restrict__ Aim, int sA,
    const float* __restrict__ Bre, const float* __restrict__ Bim, int sB,
    float* __restrict__ C0re, float* __restrict__ C0im,
    float* __restrict__ P1re, float* __restrict__ P1im, int sC,
    int N, int Kd, int split)
{
    __shared__ float As_re[2][32][66], As_im[2][32][66];
    __shared__ float Bs_re[2][32][TN+4], Bs_im[2][32][TN+4];
    const int z = blockIdx.z;
    const int w  = split ? (z >> 1) : z;
    const int kh = split ? (z & 1) : 0;
    const int kbeg = kh * (Kd >> 1);
    const int klen = split ? (Kd >> 1) : Kd;
    Are += (size_t)w * sA; Aim += (size_t)w * sA;
    Bre += (size_t)w * sB; Bim += (size_t)w * sB;
    float* Cre = (kh ? P1re : C0re) + (size_t)w * sC;
    float* Cim = (kh ? P1im : C0im) + (size_t)w * sC;
    const int tid = threadIdx.x;
    const int bm = blockIdx.y * 64, bn = blockIdx.x * TN;
    const int tm = (tid / (TN/4)) << 2;      // 0..60 (4 rows)
    const int tn = (tid % (TN/4)) << 2;      // 4 cols
    // staging assignments
    constexpr int AQ = (TN == 64) ? 2 : 4;   // float4 chunks of A k per thread
    const int lmA = (TN == 64) ? (tid >> 2) : (tid >> 1);          // 0..63
    const int lkA = (TN == 64) ? ((tid & 3) << 3) : ((tid & 1) << 4);
    const int lkB = (TN == 64) ? (tid >> 4) : (tid >> 3);          // 0..15
    const int lnB = (TN == 64) ? ((tid & 15) << 2) : ((tid & 7) << 2);
    float cr[4][4] = {{0.f}}, ci[4][4] = {{0.f}};
    const float* pAre = Are + (size_t)(bm + lmA) * Kd + kbeg + lkA;
    const float* pAim = Aim + (size_t)(bm + lmA) * Kd + kbeg + lkA;
    const float* pBre = Bre + (size_t)(kbeg + lkB) * N + bn + lnB;
    const float* pBim = Bim + (size_t)(kbeg + lkB) * N + bn + lnB;
    float4 arv[AQ], aiv[AQ], brv0, biv0, brv1, biv1;
    #pragma unroll
    for (int q = 0; q < AQ; ++q) {
        arv[q] = *(const float4*)(pAre + 4*q);
        aiv[q] = *(const float4*)(pAim + 4*q);
    }
    brv0 = *(const float4*)(pBre);
    biv0 = *(const float4*)(pBim);
    brv1 = *(const float4*)(pBre + (size_t)16 * N);
    biv1 = *(const float4*)(pBim + (size_t)16 * N);
    for (int kk = 0; kk < klen; kk += 32) {
        const int buf = (kk >> 5) & 1;
        #pragma unroll
        for (int q = 0; q < AQ; ++q) {
            const int kb = lkA + 4*q;
            As_re[buf][kb+0][lmA] = arv[q].x; As_re[buf][kb+1][lmA] = arv[q].y;
            As_re[buf][kb+2][lmA] = arv[q].z; As_re[buf][kb+3][lmA] = arv[q].w;
            As_im[buf][kb+0][lmA] = aiv[q].x; As_im[buf][kb+1][lmA] = aiv[q].y;
            As_im[buf][kb+2][lmA] = aiv[q].z; As_im[buf][kb+3][lmA] = aiv[q].w;
        }
        *(float4*)&Bs_re[buf][lkB][lnB] = brv0;
        *(float4*)&Bs_im[buf][lkB][lnB] = biv0;
        *(float4*)&Bs_re[buf][lkB+16][lnB] = brv1;
        *(float4*)&Bs_im[buf][lkB+16][lnB] = biv1;
        __syncthreads();
        const int knx = kk + 32;
        if (knx < klen) {
            #pragma unroll
            for (int q = 0; q < AQ; ++q) {
                arv[q] = *(const float4*)(pAre + knx + 4*q);
                aiv[q] = *(const float4*)(pAim + knx + 4*q);
            }
            brv0 = *(const float4*)(pBre + (size_t)knx * N);
            biv0 = *(const float4*)(pBim + (size_t)knx * N);
            brv1 = *(const float4*)(pBre + (size_t)(knx + 16) * N);
            biv1 = *(const float4*)(pBim + (size_t)(knx + 16) * N);
        }
        #pragma unroll
        for (int k = 0; k < 32; ++k) {
            const float4 xr = *(const float4*)&As_re[buf][k][tm];
            const float4 xi = *(const float4*)&As_im[buf][k][tm];
            const float4 yr = *(const float4*)&Bs_re[buf][k][tn];
            const float4 yi = *(const float4*)&Bs_im[buf][k][tn];
            const float axr[4] = {xr.x, xr.y, xr.z, xr.w};
            const float axi[4] = {xi.x, xi.y, xi.z, xi.w};
            const float byr[4] = {yr.x, yr.y, yr.z, yr.w};
            const float byi[4] = {yi.x, yi.y, yi.z, yi.w};
            #pragma unroll
            for (int i = 0; i < 4; ++i) {
                #pragma unroll
                for (int j = 0; j < 4; ++j) {
                    cr[i][j] += axr[i]*byr[j] - axi[i]*byi[j];
                    ci[i][j] += axr[i]*byi[j] + axi[i]*byr[j];
                }
            }
        }
    }
    #pragma unroll
    for (int i = 0; i < 4; ++i) {
        const size_t idx = (size_t)(bm + tm + i) * N + bn + tn;
        *(float4*)(Cre + idx) = make_float4(cr[i][0], cr[i][1], cr[i][2], cr[i][3]);
        *(float4*)(Cim + idx) = make_float4(ci[i][0], ci[i][1], ci[i][2], ci[i][3]);
    }
}

// ---------------------------------------------------------------------------
// Split-K combine + old epilogue modes, elementwise in-place on C (= P0).
// v = P0 + P1 (deterministic half0+half1), then:
//  0: C = v
//  1: C = dcoef*D - v
//  2: C = v;  U = 5.5*D + 0.5*v
//  3: C = (60.5*I + 48*D + 23*E + v)/61.5
//  4: C = 2*D + 2*v - I
// grid (256, 4): y = weight index (stride CMAT); 1 float4 per plane/thread.
// ---------------------------------------------------------------------------
__launch_bounds__(256)
__global__ void combine_kernel(float* __restrict__ C, const float* __restrict__ P1,
                               const float* __restrict__ D, const float* __restrict__ E,
                               float* __restrict__ U, float dcoef, int mode)
{
    const size_t off = (size_t)blockIdx.y * CMAT;
    const size_t idx = ((size_t)blockIdx.x * 256 + threadIdx.x) * 4;  // < PLANE
    const float4 p0r = *(const float4*)(C + off + idx);
    const float4 p0i = *(const float4*)(C + off + PLANE + idx);
    const float4 p1r = *(const float4*)(P1 + off + idx);
    const float4 p1i = *(const float4*)(P1 + off + PLANE + idx);
    float vr[4] = {p0r.x+p1r.x, p0r.y+p1r.y, p0r.z+p1r.z, p0r.w+p1r.w};
    float vi[4] = {p0i.x+p1i.x, p0i.y+p1i.y, p0i.z+p1i.z, p0i.w+p1i.w};
    const int row = (int)(idx >> 9);
    const int col = (int)(idx & 511);
    if (mode == 1) {
        const float4 dr4 = *(const float4*)(D + off + idx);
        const float4 di4 = *(const float4*)(D + off + PLANE + idx);
        const float dr[4] = {dr4.x, dr4.y, dr4.z, dr4.w};
        const float di[4] = {di4.x, di4.y, di4.z, di4.w};
        #pragma unroll
        for (int j = 0; j < 4; ++j) { vr[j] = dcoef*dr[j] - vr[j]; vi[j] = dcoef*di[j] - vi[j]; }
    } else if (mode == 2) {
        const float4 dr4 = *(const float4*)(D + off + idx);
        const float4 di4 = *(const float4*)(D + off + PLANE + idx);
        const float dr[4] = {dr4.x, dr4.y, dr4.z, dr4.w};
        const float di[4] = {di4.x, di4.y, di4.z, di4.w};
        float ur[4], ui[4];
        #pragma unroll
        for (int j = 0; j < 4; ++j) { ur[j] = 5.5f*dr[j] + 0.5f*vr[j]; ui[j] = 5.5f*di[j] + 0.5f*vi[j]; }
        *(float4*)(U + off + idx) = make_float4(ur[0], ur[1], ur[2], ur[3]);
        *(float4*)(U + off + PLANE + idx) = make_float4(ui[0], ui[1], ui[2], ui[3]);
    } else if (mode == 3) {
        const float inv61 = 1.0f/61.5f;
        const float4 sr4 = *(const float4*)(D + off + idx);
        const float4 si4 = *(const float4*)(D + off + PLANE + idx);
        const float4 tr4 = *(const float4*)(E + off + idx);
        const float4 ti4 = *(const float4*)(E + off + PLANE + idx);
        const float sr[4] = {sr4.x, sr4.y, sr4.z, sr4.w};
        const float si[4] = {si4.x, si4.y, si4.z, si4.w};
        const float tr[4] = {tr4.x, tr4.y, tr4.z, tr4.w};
        const float ti[4] = {ti4.x, ti4.y, ti4.z, ti4.w};
        #pragma unroll
        for (int j = 0; j < 4; ++j) {
            const float diag = (row == col + j) ? 60.5f : 0.0f;
            vr[j] = (diag + 48.f*sr[j] + 23.f*tr[j] + vr[j]) * inv61;
            vi[j] = (       48.f*si[j] + 23.f*ti[j] + vi[j]) * inv61;
        }
    } else if (mode == 4) {
        const float4 dr4 = *(const float4*)(D + off + idx);
        const float4 di4 = *(const float4*)(D + off + PLANE + idx);
        const float dr[4] = {dr4.x, dr4.y, dr4.z, dr4.w};
        const float di[4] = {di4.x, di4.y, di4.z, di4.w};
        #pragma unroll
        for (int j = 0; j < 4; ++j) {
            const float diag = (row == col + j) ? 1.0f : 0.0f;
            vr[j] = 2.f*dr[j] + 2.f*vr[j] - diag;
            vi[j] = 2.f*di[j] + 2.f*vi[j];
        }
    }
    *(float4*)(C + off + idx) = make_float4(vr[0], vr[1], vr[2], vr[3]);
    *(float4*)(C + off + PLANE + idx) = make_float4(vi[0], vi[1], vi[2], vi[3]);
}

// ---------------------------------------------------------------------------
// 32x64 / 2x4 legacy core — out-proj only (mode 5: bounded d_out stores).
// ---------------------------------------------------------------------------
__launch_bounds__(256)
__global__ void cgemm_kernel(
    const float* __restrict__ Are, const float* __restrict__ Aim, int sA,
    const float* __restrict__ Bre, const float* __restrict__ Bim, int sB,
    float* __restrict__ Cre, float* __restrict__ Cim, int sC,
    int M, int N, int Kd, int mode, int out_floats)
{
    __shared__ float As_re[2][32][34], As_im[2][32][34];
    __shared__ float Bs_re[2][32][68], Bs_im[2][32][68];
    const int b = blockIdx.z;
    Are += (size_t)b * sA; Aim += (size_t)b * sA;
    Bre += (size_t)b * sB; Bim += (size_t)b * sB;
    Cre += (size_t)b * sC; Cim += (size_t)b * sC;
    const int bnd = mode == 5 ? (out_floats - b * sC) : 0;
    const int tid = threadIdx.x;
    const int bm = blockIdx.y * 32, bn = blockIdx.x * 64;
    const int tm = (tid >> 4) << 1;
    const int tn = (tid & 15) << 2;
    const int lmA = tid >> 3;
    const int lkA = (tid & 7) << 2;
    const int lkB = tid >> 4;
    const int lnB = (tid & 15) << 2;
    float cr[2][4] = {{0.f}}, ci[2][4] = {{0.f}};
    const float* pAre = Are + (size_t)(bm + lmA) * Kd + lkA;
    const float* pAim = Aim + (size_t)(bm + lmA) * Kd + lkA;
    const float* pBre = Bre + (size_t)lkB * N + bn + lnB;
    const float* pBim = Bim + (size_t)lkB * N + bn + lnB;
    float4 ar  = *(const float4*)(pAre);
    float4 ai  = *(const float4*)(pAim);
    float4 br0 = *(const float4*)(pBre);
    float4 bi0 = *(const float4*)(pBim);
    float4 br1 = *(const float4*)(pBre + (size_t)16 * N);
    float4 bi1 = *(const float4*)(pBim + (size_t)16 * N);
    for (int k0 = 0; k0 < Kd; k0 += 32) {
        const int buf = (k0 >> 5) & 1;
        As_re[buf][lkA+0][lmA] = ar.x; As_re[buf][lkA+1][lmA] = ar.y;
        As_re[buf][lkA+2][lmA] = ar.z; As_re[buf][lkA+3][lmA] = ar.w;
        As_im[buf][lkA+0][lmA] = ai.x; As_im[buf][lkA+1][lmA] = ai.y;
        As_im[buf][lkA+2][lmA] = ai.z; As_im[buf][lkA+3][lmA] = ai.w;
        *(float4*)&Bs_re[buf][lkB][lnB] = br0;
        *(float4*)&Bs_im[buf][lkB][lnB] = bi0;
        *(float4*)&Bs_re[buf][lkB+16][lnB] = br1;
        *(float4*)&Bs_im[buf][lkB+16][lnB] = bi1;
        __syncthreads();
        const int kn = k0 + 32;
        if (kn < Kd) {
            ar  = *(const float4*)(pAre + kn);
            ai  = *(const float4*)(pAim + kn);
            br0 = *(const float4*)(pBre + (size_t)kn * N);
            bi0 = *(const float4*)(pBim + (size_t)kn * N);
            br1 = *(const float4*)(pBre + (size_t)(kn + 16) * N);
            bi1 = *(const float4*)(pBim + (size_t)(kn + 16) * N);
        }
        #pragma unroll
        for (int k = 0; k < 32; ++k) {
            const float2 xr = *(const float2*)&As_re[buf][k][tm];
            const float2 xi = *(const float2*)&As_im[buf][k][tm];
            const float4 yr = *(const float4*)&Bs_re[buf][k][tn];
            const float4 yi = *(const float4*)&Bs_im[buf][k][tn];
            const float axr[2] = {xr.x, xr.y};
            const float axi[2] = {xi.x, xi.y};
            const float byr[4] = {yr.x, yr.y, yr.z, yr.w};
            const float byi[4] = {yi.x, yi.y, yi.z, yi.w};
            #pragma unroll
            for (int i = 0; i < 2; ++i) {
                #pragma unroll
                for (int j = 0; j < 4; ++j) {
                    cr[i][j] += axr[i]*byr[j] - axi[i]*byi[j];
                    ci[i][j] += axr[i]*byi[j] + axi[i]*byr[j];
                }
            }
        }
    }
    #pragma unroll
    for (int i = 0; i < 2; ++i) {
        const size_t idx = (size_t)(bm + tm + i) * N + bn + tn;
        float vr[4] = {cr[i][0], cr[i][1], cr[i][2], cr[i][3]};
        float vi[4] = {ci[i][0], ci[i][1], ci[i][2], ci[i][3]};
        if (mode == 5) {
            #pragma unroll
            for (int j = 0; j < 4; ++j) {
                const size_t ire = idx + j;
                const size_t iim = (size_t)PPLANE + idx + j;
                if (ire < (size_t)bnd) Cre[ire] = vr[j];
                if (iim < (size_t)bnd) Cre[iim] = vi[j];
            }
        } else {
            *(float4*)(Cre + idx) = make_float4(vr[0], vr[1], vr[2], vr[3]);
            *(float4*)(Cim + idx) = make_float4(vi[0], vi[1], vi[2], vi[3]);
        }
    }
}

// A = 0.02*((Mre - Mre^T) + i(Mim + Mim^T)) for all 4 weights (blockIdx.y).
__launch_bounds__(256)
__global__ void build_A_kernel(const float* __restrict__ W0re, const float* __restrict__ W0im,
                               const float* __restrict__ W1re, const float* __restrict__ W1im,
                               const float* __restrict__ W2re, const float* __restrict__ W2im,
                               const float* __restrict__ W3re, const float* __restrict__ W3im,
                               int aoff)
{
    float* Aout = g_pool + aoff;
    const int w = blockIdx.y;
    const float* Mre; const float* Mim;
    if      (w == 0) { Mre = W0re; Mim = W0im; }
    else if (w == 1) { Mre = W1re; Mim = W1im; }
    else if (w == 2) { Mre = W2re; Mim = W2im; }
    else             { Mre = W3re; Mim = W3im; }
    const int idx = blockIdx.x * 256 + threadIdx.x;   // < 262144
    const int i = idx >> 9, j = idx & 511;
    float* Are = Aout + (size_t)w * CMAT;
    float* Aim = Are + PLANE;
    Are[idx] = 0.02f * (Mre[i*512 + j] - Mre[j*512 + i]);
    Aim[idx] = 0.02f * (Mim[i*512 + j] + Mim[j*512 + i]);
}

__launch_bounds__(256)
__global__ void zero_kernel(float* __restrict__ p, int n)
{
    const int i = blockIdx.x * 256 + threadIdx.x;
    if (i < n) p[i] = 0.f;
}

// All heads: b2[h,n,s] = |conj(Q[n,h,:]) . K[s,h,:]|^2 * SCALE^2, + row sums.
__launch_bounds__(256)
__global__ void scores_kernel(const float* __restrict__ Qre, const float* __restrict__ Qim,
                              const float* __restrict__ Kre, const float* __restrict__ Kim,
                              float* __restrict__ B2, float* __restrict__ RS)
{
    __shared__ float Qs_re[16][68], Qs_im[16][68], Ks_re[16][68], Ks_im[16][68];
    __shared__ float rs[64];
    const int h = blockIdx.z;
    const int bm = blockIdx.y * 64, bn = blockIdx.x * 64;
    const int tid = threadIdx.x;
    const int tm = (tid >> 4) << 2, tn = (tid & 15) << 2;
    const int lm = tid >> 2, lk = (tid & 3) << 2;
    float dr[4][4] = {{0.f}}, di[4][4] = {{0.f}};
    for (int k0 = 0; k0 < 64; k0 += 16) {
        const float4 qr = *(const float4*)(Qre + (size_t)(bm+lm)*512 + h*64 + k0 + lk);
        const float4 qi = *(const float4*)(Qim + (size_t)(bm+lm)*512 + h*64 + k0 + lk);
        const float4 kr = *(const float4*)(Kre + (size_t)(bn+lm)*512 + h*64 + k0 + lk);
        const float4 ki = *(const float4*)(Kim + (size_t)(bn+lm)*512 + h*64 + k0 + lk);
        __syncthreads();
        Qs_re[lk+0][lm]=qr.x; Qs_re[lk+1][lm]=qr.y; Qs_re[lk+2][lm]=qr.z; Qs_re[lk+3][lm]=qr.w;
        Qs_im[lk+0][lm]=qi.x; Qs_im[lk+1][lm]=qi.y; Qs_im[lk+2][lm]=qi.z; Qs_im[lk+3][lm]=qi.w;
        Ks_re[lk+0][lm]=kr.x; Ks_re[lk+1][lm]=kr.y; Ks_re[lk+2][lm]=kr.z; Ks_re[lk+3][lm]=kr.w;
        Ks_im[lk+0][lm]=ki.x; Ks_im[lk+1][lm]=ki.y; Ks_im[lk+2][lm]=ki.z; Ks_im[lk+3][lm]=ki.w;
        __syncthreads();
        #pragma unroll
        for (int k = 0; k < 16; ++k) {
            const float4 xr = *(const float4*)&Qs_re[k][tm];
            const float4 xi = *(const float4*)&Qs_im[k][tm];
            const float4 yr = *(const float4*)&Ks_re[k][tn];
            const float4 yi = *(const float4*)&Ks_im[k][tn];
            const float axr[4] = {xr.x, xr.y, xr.z, xr.w};
            const float axi[4] = {xi.x, xi.y, xi.z, xi.w};
            const float byr[4] = {yr.x, yr.y, yr.z, yr.w};
            const float byi[4] = {yi.x, yi.y, yi.z, yi.w};
            #pragma unroll
            for (int i = 0; i < 4; ++i) {
                #pragma unroll
                for (int j = 0; j < 4; ++j) {
                    dr[i][j] += axr[i]*byr[j] + axi[i]*byi[j];   // re(conj(q)*k)
                    di[i][j] += axr[i]*byi[j] - axi[i]*byr[j];   // im(conj(q)*k)
                }
            }
        }
    }
    if (tid < 64) rs[tid] = 0.f;
    __syncthreads();
    float rpart[4] = {0.f, 0.f, 0.f, 0.f};
    #pragma unroll
    for (int i = 0; i < 4; ++i) {
        #pragma unroll
        for (int j = 0; j < 4; ++j) {
            const float b2v = (dr[i][j]*dr[i][j] + di[i][j]*di[i][j]) * 0.015625f;
            B2[(size_t)h*1048576 + (size_t)(bm+tm+i)*1024 + (bn+tn+j)] = b2v;
            rpart[i] += b2v;
        }
    }
    #pragma unroll
    for (int i = 0; i < 4; ++i) atomicAdd(&rs[tm+i], rpart[i]);
    __syncthreads();
    if (tid < 64) atomicAdd(&RS[h*1024 + bm + tid], rs[tid]);
}

// Per (h,n) row: exact top-102 radix select, softmax, weighted V gather.
__launch_bounds__(256)
__global__ void select_kernel(const float* __restrict__ B2, const float* __restrict__ RS,
                              const float* __restrict__ Vre, const float* __restrict__ Vim,
                              float* __restrict__ AOre, float* __restrict__ AOim)
{
    __shared__ float sv[1024];
    __shared__ unsigned int hist[256];
    __shared__ int ssum[256];
    __shared__ unsigned int sc[4];
    __shared__ float sel_v[104];
    __shared__ int sel_i[104];
    __shared__ float sel_w[104];
    __shared__ float rbuf[256];
    const int bid = blockIdx.x;
    const int h = bid >> 10, n = bid & 1023;
    const int tid = threadIdx.x;
    const float* row = B2 + (size_t)h * 1048576 + (size_t)n * 1024;
    #pragma unroll
    for (int e = 0; e < 4; ++e) sv[tid + 256*e] = row[tid + 256*e];
    if (tid == 0) sc[2] = 0u;
    __syncthreads();

    unsigned prefix = 0u, pmask = 0u;
    int krem = KTOP;
    for (int pass = 0; pass < 4; ++pass) {
        const int shift = 24 - 8 * pass;
        hist[tid] = 0u;
        __syncthreads();
        #pragma unroll
        for (int e = 0; e < 4; ++e) {
            const unsigned u = __float_as_uint(sv[tid + 256*e]);
            if ((u & pmask) == prefix) atomicAdd(&hist[(u >> shift) & 255u], 1u);
        }
        __syncthreads();
        ssum[tid] = (int)hist[tid];
        __syncthreads();
        for (int off = 1; off < 256; off <<= 1) {
            const int add = (tid + off < 256) ? ssum[tid + off] : 0;
            __syncthreads();
            ssum[tid] += add;
            __syncthreads();
        }
        const int above = (tid < 255) ? ssum[tid + 1] : 0;
        if (ssum[tid] >= krem && above < krem) {
            sc[0] = (unsigned)tid;
            sc[1] = (unsigned)(krem - above);
        }
        __syncthreads();
        prefix |= sc[0] << shift;
        pmask |= 0xFFu << shift;
        krem = (int)sc[1];
        __syncthreads();
    }
    const unsigned T = prefix;
    const int m = krem;   // ties at T: lowest indices first (jax top_k order)

    #pragma unroll
    for (int e = 0; e < 4; ++e) {
        const int i = tid + 256*e;
        const float v = sv[i];
        const unsigned u = __float_as_uint(v);
        bool sel = (u > T);
        if (!sel && u == T) {
            int rank = 0;
            for (int j = 0; j < i; ++j) rank += (__float_as_uint(sv[j]) == T) ? 1 : 0;
            sel = (rank < m);
        }
        if (sel) {
            const unsigned p = atomicAdd(&sc[2], 1u);
            if (p < 104u) { sel_v[p] = v; sel_i[p] = i; }
        }
    }
    __syncthreads();

    rbuf[tid] = (tid < KTOP) ? sel_v[tid] : 0.f;
    __syncthreads();
    for (int st = 128; st > 0; st >>= 1) { if (tid < st) rbuf[tid] += rbuf[tid + st]; __syncthreads(); }
    const float sumtop = rbuf[0];
    __syncthreads();
    rbuf[tid] = (tid < KTOP) ? sel_v[tid] : -1.f;
    __syncthreads();
    for (int st = 128; st > 0; st >>= 1) { if (tid < st) rbuf[tid] = fmaxf(rbuf[tid], rbuf[tid + st]); __syncthreads(); }
    const float vmax = rbuf[0];
    __syncthreads();

    const float S_row = RS[(h << 10) + n];
    const float denom = sumtop + 1e-8f * S_row;    // == (sum tp + 1e-8) * S_row
    const float scl = (float)KTOP / denom;
    if (tid < KTOP) sel_w[tid] = expf(sel_v[tid] * scl - vmax * scl);
    __syncthreads();
    rbuf[tid] = (tid < KTOP) ? sel_w[tid] : 0.f;
    __syncthreads();
    for (int st = 128; st > 0; st >>= 1) { if (tid < st) rbuf[tid] += rbuf[tid + st]; __syncthreads(); }
    const float Z = rbuf[0];
    __syncthreads();

    if (tid < 128) {
        const int d = tid & 63;
        const int im = tid >> 6;
        const float* Vp = im ? Vim : Vre;
        const int base = h * 64 + d;
        float acc = 0.f;
        for (int j = 0; j < KTOP; ++j) acc += sel_w[j] * Vp[(size_t)sel_i[j] * 512 + base];
        acc /= Z;
        float* AOp = im ? AOim : AOre;
        AOp[(size_t)n * 512 + h * 64 + d] = acc;
    }
}

// ---------------------------------------------------------------------------
extern "C" void kernel_launch(void* const* d_in, const int* in_sizes, int n_in,
                              void* d_out, int out_size, void* d_ws, size_t ws_size,
                              hipStream_t stream)
{
    (void)in_sizes; (void)n_in; (void)d_ws; (void)ws_size;
    const float* x_re = (const float*)d_in[0];
    const float* x_im = (const float*)d_in[1];
    // d_in[10..13] (phase MLP) are dead code.

    float* pool = nullptr;
    hipGetSymbolAddress((void**)&pool, HIP_SYMBOL(g_pool));   // query only; capture-safe

    float* Wall = pool;                // 4 complex 512^2: [W0re|W0im|W1re|...]
    float* RSg  = Wall + 4*CMAT;       // 8192 row sums (8 heads x 1024)
    float* R    = RSg + 8192;          // union region
    // Phase A (all 4 weights batched): 6 buffers x 4 weights x CMAT + P1
    float* A   = R;
    float* S   = R + 4*CMAT;
    float* S2  = R + 8*CMAT;
    float* X   = R + 12*CMAT;          // U, then NS ping
    float* X2  = R + 16*CMAT;          // X0, then NS pong
    float* T   = R + 20*CMAT;          // NS temp
    float* P1g = R + 24*CMAT;          // split-K second partial (4 weights)
    // Phase B (overlays the same region):
    float* Q  = R;                     // CPROJ floats each
    float* Kp = R + CPROJ;
    float* V  = R + 2*CPROJ;
    float* AO = R + 3*CPROJ;
    float* B2 = R + 4*CPROJ;           // 8 x 1024x1024

    const int aoff = (int)(A - pool);
    float* P1re = P1g; float* P1im = P1g + PLANE;   // stride CMAT per weight
    const dim3 gA(8, 8, 8);            // split-K=2: z = w*2 + khalf
    const dim3 gC(256, 4);

    // ---- Phase A: Cayley unitaries, split-K 4x4 core + combines ----
    build_A_kernel<<<dim3(1024,4),256,0,stream>>>(
        (const float*)d_in[2],(const float*)d_in[3],(const float*)d_in[4],(const float*)d_in[5],
        (const float*)d_in[6],(const float*)d_in[7],(const float*)d_in[8],(const float*)d_in[9], aoff);
    // S = A*A
    cgemm44_kernel<64><<<gA,256,0,stream>>>(A,A+PLANE,CMAT, A,A+PLANE,CMAT,
                                            S,S+PLANE, P1re,P1im, CMAT, 512,512, 1);
    combine_kernel<<<gC,256,0,stream>>>(S, P1g, nullptr, nullptr, nullptr, 0.f, 0);
    // S2 = S*S;  U = 5.5 S + 0.5 S2 -> X slot
    cgemm44_kernel<64><<<gA,256,0,stream>>>(S,S+PLANE,CMAT, S,S+PLANE,CMAT,
                                            S2,S2+PLANE, P1re,P1im, CMAT, 512,512, 1);
    combine_kernel<<<gC,256,0,stream>>>(S2, P1g, S, nullptr, X, 0.f, 2);
    // X0 = (60.5 I + 48 S + 23 S2 + S2*U)/61.5 -> X2
    cgemm44_kernel<64><<<gA,256,0,stream>>>(S2,S2+PLANE,CMAT, X,X+PLANE,CMAT,
                                            X2,X2+PLANE, P1re,P1im, CMAT, 512,512, 1);
    combine_kernel<<<gC,256,0,stream>>>(X2, P1g, S, S2, nullptr, 0.f, 3);
    // 2 Newton-Schulz iterations: X <- X(2I - (I-S) X)
    float* Xc = X2; float* Xn = X;     // X0 lives in X2; X slot (U) is dead
    for (int it = 0; it < 2; ++it) {
        // T = 1*Xc - S*Xc
        cgemm44_kernel<64><<<gA,256,0,stream>>>(S,S+PLANE,CMAT, Xc,Xc+PLANE,CMAT,
                                                T,T+PLANE, P1re,P1im, CMAT, 512,512, 1);
        combine_kernel<<<gC,256,0,stream>>>(T, P1g, Xc, nullptr, nullptr, 1.f, 1);
        // Xn = 2*Xc - Xc*T
        cgemm44_kernel<64><<<gA,256,0,stream>>>(Xc,Xc+PLANE,CMAT, T,T+PLANE,CMAT,
                                                Xn,Xn+PLANE, P1re,P1im, CMAT, 512,512, 1);
        combine_kernel<<<gC,256,0,stream>>>(Xn, P1g, Xc, nullptr, nullptr, 2.f, 1);
        float* tmp = Xc; Xc = Xn; Xn = tmp;
    }
    // W = 2X + 2*A*X - I -> Wall   [= (I-A)^{-1}(I+A)]
    cgemm44_kernel<64><<<gA,256,0,stream>>>(A,A+PLANE,CMAT, Xc,Xc+PLANE,CMAT,
                                            Wall,Wall+PLANE, P1re,P1im, CMAT, 512,512, 1);
    combine_kernel<<<gC,256,0,stream>>>(Wall, P1g, Xc, nullptr, nullptr, 0.f, 4);

    // ---- Phase B: Q,K,V = x @ W[0..2] (4x4 core, 64x32 tiles, no k-split;
    //      bit-exact core swap per R17 absmax evidence) ----
    cgemm44_kernel<32><<<dim3(16,16,3),128,0,stream>>>(x_re,x_im,0, Wall,Wall+PLANE,CMAT,
                                                       Q,Q+PPLANE, nullptr,nullptr, CPROJ,
                                                       512,512, 0);

    zero_kernel<<<32,256,0,stream>>>(RSg, 8192);
    scores_kernel<<<dim3(16,16,8),256,0,stream>>>(Q,Q+PPLANE, Kp,Kp+PPLANE, B2, RSg);
    select_kernel<<<8192,256,0,stream>>>(B2, RSg, V,V+PPLANE, AO,AO+PPLANE);

    // ---- Output projection straight to d_out (mode 5: bounded scalar) ----
    // z=2 row-halves via sA=sC=PLANE; bnd = out_floats - b*PLANE inside.
    cgemm_kernel<<<dim3(8,16,2),256,0,stream>>>(AO,AO+PPLANE,PLANE, Wall+3*CMAT,Wall+3*CMAT+PLANE,0,
                                                (float*)d_out,nullptr,PLANE, 512,512,512, 5, out_size);
}

// Round 5
// 1019.161 us; speedup vs baseline: 1.1762x; 1.1762x over previous
//
#include <hip/hip_runtime.h>
#include <math.h>

// ---------------------------------------------------------------------------
// QuantumSuperpositionAttention  (B=1, N=1024, DIM=512, H=8, DH=64, k=102)
//
// Identities:
//  * phase MLP is dead code: |alpha * e^{i phi}|^2 == |alpha|^2
//  * cayley(M): A = 0.02*((Mre - Mre^T) + i(Mim + Mim^T));
//    W = (I-A)^{-1}(I+A) = 2(I+A)X - I,  X = inv(I - A^2), spec [1,5).
//  * inv: deg-4 minimax init (PS form) + 2 quadratic NS -> rho ~ 7e-8.
//  * GEMM CORE LESSONS (R9..R18): the 32x64/2x4/BK=32 dbuf core at >=2
//    blocks/CU is the local optimum (~82us phase-A, ~123us QKV); LDS read
//    BW is the structural wall (67% VALU ceiling). 4x4 microtiles regress
//    at low occupancy; split-K+combine is a net loss. DO NOT TOUCH.
//  * ERROR BUDGET (R6..R19 calibrated): W-chain realization changes at
//    fp32 floor (~1e-7) are SAFE (R18 split-K passed, absmax 0.00195).
//    Residual 4.3e-6 FAILED (R19 cubic NS: absmax 0.0146 > 0.0109 thr).
//    Baseline absmax 0.01025 = 94% of threshold: top-k ties have NO slack.
//    => NS chain stays: deg-4 init + 2 quadratic NS (8 GEMMs). CLOSED.
//  * ACCURACY RULES (R7/R9): never change summation ORDER anywhere in the
//    Wq/Wk/Q/K/scores chain (pre-top-k). Post-top-k (out-proj) untouched
//    too: bf16-rounding flips near ulp boundaries are a real risk.
//  * D_OUT BOUNDS RULE (R10/R11): every d_out store bounds-checked.
//
// R20: revert to R16 (proven 1003us PASS) + full-K scores staging:
//  * scores_kernel stages all K=64 once (LDS 69.9KB, 2 blocks/CU) ->
//    1 barrier instead of 8, no inter-tile global stalls. Summation order
//    per element IDENTICAL (ascending k 0..63) -> bit-identical output.
// ---------------------------------------------------------------------------

#define PLANE   262144      // 512*512
#define CMAT    524288      // floats per complex 512x512 (2 MB)
#define PPLANE  524288      // 1024*512
#define CPROJ   1048576     // floats per complex 1024x512 (4 MB)
#define KTOP    102

#define R_FLOATS 12582912
#define POOL_FLOATS (4*CMAT + 8192 + R_FLOATS)
__device__ __attribute__((aligned(256))) float g_pool[POOL_FLOATS];

// ---------------------------------------------------------------------------
// Complex planar GEMM, R16 core: 32x64 C-tile / 256 thr / 2x4 microtile /
// BK=32 / LDS double-buffer + reg prefetch. Grid (N/64, M/32, batch).
// Epilogue modes:
//  0: C = A*B
//  1: C = dcoef*D - A*B                       (NS steps)
//  2: C = A*B (=S2);  E = 5.5*D + 0.5*C      (D=S, E=U)
//  3: C = (60.5*I + 48*D + 23*E + A*B)/61.5  (D=S, E=S2; C=X0)
//  4: C = 2*D + 2*A*B - I                    (D=X; C=W)
//  5: C = A*B, scalar stores bounded by out_floats; im plane at +PPLANE
//     (bnd = out_floats - b*sC; global im index = b*sC + PPLANE + idx)
// ---------------------------------------------------------------------------
__launch_bounds__(256)
__global__ void cgemm_kernel(
    const float* __restrict__ Are, const float* __restrict__ Aim, int sA,
    const float* __restrict__ Bre, const float* __restrict__ Bim, int sB,
    const float* __restrict__ Dre, const float* __restrict__ Dim, int sD,
    const float* __restrict__ Ere2, float* __restrict__ Ewr, int sE,
    float* __restrict__ Cre, float* __restrict__ Cim, int sC,
    int M, int N, int Kd, float dcoef, int mode, int out_floats)
{
    __shared__ float As_re[2][32][34], As_im[2][32][34];
    __shared__ float Bs_re[2][32][68], Bs_im[2][32][68];
    const int b = blockIdx.z;
    Are += (size_t)b * sA; Aim += (size_t)b * sA;
    Bre += (size_t)b * sB; Bim += (size_t)b * sB;
    Dre += (size_t)b * sD; Dim += (size_t)b * sD;
    const float* Ere = Ere2 + (size_t)b * sE;
    const float* Eim = Ere + PLANE;      // E input (S2) planes
    float* Uwr = Ewr ? (Ewr + (size_t)b * sE) : (float*)0;
    Cre += (size_t)b * sC; Cim += (size_t)b * sC;
    const int bnd = mode == 5 ? (out_floats - b * sC) : 0;
    const int tid = threadIdx.x;
    const int bm = blockIdx.y * 32, bn = blockIdx.x * 64;
    const int tm = (tid >> 4) << 1;      // 0..30 (2 rows)
    const int tn = (tid & 15) << 2;      // 0..60 (4 cols)
    const int lmA = tid >> 3;            // 0..31
    const int lkA = (tid & 7) << 2;      // 0,4..28
    const int lkB = tid >> 4;            // 0..15
    const int lnB = (tid & 15) << 2;     // 0..60
    float cr[2][4] = {{0.f}}, ci[2][4] = {{0.f}};
    const float* pAre = Are + (size_t)(bm + lmA) * Kd + lkA;
    const float* pAim = Aim + (size_t)(bm + lmA) * Kd + lkA;
    const float* pBre = Bre + (size_t)lkB * N + bn + lnB;
    const float* pBim = Bim + (size_t)lkB * N + bn + lnB;
    // preload K-tile 0 into registers
    float4 ar  = *(const float4*)(pAre);
    float4 ai  = *(const float4*)(pAim);
    float4 br0 = *(const float4*)(pBre);
    float4 bi0 = *(const float4*)(pBim);
    float4 br1 = *(const float4*)(pBre + (size_t)16 * N);
    float4 bi1 = *(const float4*)(pBim + (size_t)16 * N);
    for (int k0 = 0; k0 < Kd; k0 += 32) {
        const int buf = (k0 >> 5) & 1;
        As_re[buf][lkA+0][lmA] = ar.x; As_re[buf][lkA+1][lmA] = ar.y;
        As_re[buf][lkA+2][lmA] = ar.z; As_re[buf][lkA+3][lmA] = ar.w;
        As_im[buf][lkA+0][lmA] = ai.x; As_im[buf][lkA+1][lmA] = ai.y;
        As_im[buf][lkA+2][lmA] = ai.z; As_im[buf][lkA+3][lmA] = ai.w;
        *(float4*)&Bs_re[buf][lkB][lnB] = br0;
        *(float4*)&Bs_im[buf][lkB][lnB] = bi0;
        *(float4*)&Bs_re[buf][lkB+16][lnB] = br1;
        *(float4*)&Bs_im[buf][lkB+16][lnB] = bi1;
        __syncthreads();
        // issue next tile's global loads; latency hides under compute below
        const int kn = k0 + 32;
        if (kn < Kd) {
            ar  = *(const float4*)(pAre + kn);
            ai  = *(const float4*)(pAim + kn);
            br0 = *(const float4*)(pBre + (size_t)kn * N);
            bi0 = *(const float4*)(pBim + (size_t)kn * N);
            br1 = *(const float4*)(pBre + (size_t)(kn + 16) * N);
            bi1 = *(const float4*)(pBim + (size_t)(kn + 16) * N);
        }
        #pragma unroll
        for (int k = 0; k < 32; ++k) {
            const float2 xr = *(const float2*)&As_re[buf][k][tm];
            const float2 xi = *(const float2*)&As_im[buf][k][tm];
            const float4 yr = *(const float4*)&Bs_re[buf][k][tn];
            const float4 yi = *(const float4*)&Bs_im[buf][k][tn];
            const float axr[2] = {xr.x, xr.y};
            const float axi[2] = {xi.x, xi.y};
            const float byr[4] = {yr.x, yr.y, yr.z, yr.w};
            const float byi[4] = {yi.x, yi.y, yi.z, yi.w};
            #pragma unroll
            for (int i = 0; i < 2; ++i) {
                #pragma unroll
                for (int j = 0; j < 4; ++j) {
                    cr[i][j] += axr[i]*byr[j] - axi[i]*byi[j];
                    ci[i][j] += axr[i]*byi[j] + axi[i]*byr[j];
                }
            }
        }
    }
    #pragma unroll
    for (int i = 0; i < 2; ++i) {
        const int row = bm + tm + i;
        const size_t idx = (size_t)row * N + bn + tn;
        float vr[4] = {cr[i][0], cr[i][1], cr[i][2], cr[i][3]};
        float vi[4] = {ci[i][0], ci[i][1], ci[i][2], ci[i][3]};
        if (mode == 1) {
            const float4 dr4 = *(const float4*)(Dre + idx);
            const float4 di4 = *(const float4*)(Dim + idx);
            const float dr[4] = {dr4.x, dr4.y, dr4.z, dr4.w};
            const float di[4] = {di4.x, di4.y, di4.z, di4.w};
            #pragma unroll
            for (int j = 0; j < 4; ++j) { vr[j] = dcoef*dr[j] - vr[j]; vi[j] = dcoef*di[j] - vi[j]; }
        } else if (mode == 2) {
            const float4 dr4 = *(const float4*)(Dre + idx);
            const float4 di4 = *(const float4*)(Dim + idx);
            const float dr[4] = {dr4.x, dr4.y, dr4.z, dr4.w};
            const float di[4] = {di4.x, di4.y, di4.z, di4.w};
            float ur[4], ui[4];
            #pragma unroll
            for (int j = 0; j < 4; ++j) { ur[j] = 5.5f*dr[j] + 0.5f*vr[j]; ui[j] = 5.5f*di[j] + 0.5f*vi[j]; }
            *(float4*)(Uwr + idx) = make_float4(ur[0], ur[1], ur[2], ur[3]);
            *(float4*)(Uwr + PLANE + idx) = make_float4(ui[0], ui[1], ui[2], ui[3]);
        } else if (mode == 3) {
            const float inv61 = 1.0f/61.5f;
            const float4 sr4 = *(const float4*)(Dre + idx);
            const float4 si4 = *(const float4*)(Dim + idx);
            const float4 s2r = *(const float4*)(Ere + idx);
            const float4 s2i = *(const float4*)(Eim + idx);
            const float sr[4] = {sr4.x, sr4.y, sr4.z, sr4.w};
            const float si[4] = {si4.x, si4.y, si4.z, si4.w};
            const float tr[4] = {s2r.x, s2r.y, s2r.z, s2r.w};
            const float ti[4] = {s2i.x, s2i.y, s2i.z, s2i.w};
            #pragma unroll
            for (int j = 0; j < 4; ++j) {
                const float diag = (row == bn + tn + j) ? 60.5f : 0.0f;
                vr[j] = (diag + 48.f*sr[j] + 23.f*tr[j] + vr[j]) * inv61;
                vi[j] = (       48.f*si[j] + 23.f*ti[j] + vi[j]) * inv61;
            }
        } else if (mode == 4) {
            const float4 dr4 = *(const float4*)(Dre + idx);
            const float4 di4 = *(const float4*)(Dim + idx);
            const float dr[4] = {dr4.x, dr4.y, dr4.z, dr4.w};
            const float di[4] = {di4.x, di4.y, di4.z, di4.w};
            #pragma unroll
            for (int j = 0; j < 4; ++j) {
                const float diag = (row == bn + tn + j) ? 1.0f : 0.0f;
                vr[j] = 2.f*dr[j] + 2.f*vr[j] - diag;
                vi[j] = 2.f*di[j] + 2.f*vi[j];
            }
        }
        if (mode == 5) {
            // bounded scalar stores straight to d_out (copy_out semantics)
            #pragma unroll
            for (int j = 0; j < 4; ++j) {
                const size_t ire = idx + j;
                const size_t iim = (size_t)PPLANE + idx + j;
                if (ire < (size_t)bnd) Cre[ire] = vr[j];
                if (iim < (size_t)bnd) Cre[iim] = vi[j];
            }
        } else {
            *(float4*)(Cre + idx) = make_float4(vr[0], vr[1], vr[2], vr[3]);
            *(float4*)(Cim + idx) = make_float4(vi[0], vi[1], vi[2], vi[3]);
        }
    }
}

// A = 0.02*((Mre - Mre^T) + i(Mim + Mim^T)) for all 4 weights (blockIdx.y).
__launch_bounds__(256)
__global__ void build_A_kernel(const float* __restrict__ W0re, const float* __restrict__ W0im,
                               const float* __restrict__ W1re, const float* __restrict__ W1im,
                               const float* __restrict__ W2re, const float* __restrict__ W2im,
                               const float* __restrict__ W3re, const float* __restrict__ W3im,
                               int aoff)
{
    float* Aout = g_pool + aoff;
    const int w = blockIdx.y;
    const float* Mre; const float* Mim;
    if      (w == 0) { Mre = W0re; Mim = W0im; }
    else if (w == 1) { Mre = W1re; Mim = W1im; }
    else if (w == 2) { Mre = W2re; Mim = W2im; }
    else             { Mre = W3re; Mim = W3im; }
    const int idx = blockIdx.x * 256 + threadIdx.x;   // < 262144
    const int i = idx >> 9, j = idx & 511;
    float* Are = Aout + (size_t)w * CMAT;
    float* Aim = Are + PLANE;
    Are[idx] = 0.02f * (Mre[i*512 + j] - Mre[j*512 + i]);
    Aim[idx] = 0.02f * (Mim[i*512 + j] + Mim[j*512 + i]);
}

__launch_bounds__(256)
__global__ void zero_kernel(float* __restrict__ p, int n)
{
    const int i = blockIdx.x * 256 + threadIdx.x;
    if (i < n) p[i] = 0.f;
}

// All heads: b2[h,n,s] = |conj(Q[n,h,:]) . K[s,h,:]|^2 * SCALE^2, + row sums.
// R20: full-K (=DH=64) staged once; 1 barrier; identical ascending-k order.
__launch_bounds__(256)
__global__ void scores_kernel(const float* __restrict__ Qre, const float* __restrict__ Qim,
                              const float* __restrict__ Kre, const float* __restrict__ Kim,
                              float* __restrict__ B2, float* __restrict__ RS)
{
    __shared__ float Qs_re[64][68], Qs_im[64][68], Ks_re[64][68], Ks_im[64][68];
    __shared__ float rs[64];
    const int h = blockIdx.z;
    const int bm = blockIdx.y * 64, bn = blockIdx.x * 64;
    const int tid = threadIdx.x;
    const int tm = (tid >> 4) << 2, tn = (tid & 15) << 2;
    const int lm = tid >> 2;            // 0..63 (tile row)
    const int lk = (tid & 3) << 4;      // 0,16,32,48 (k-chunk base)
    // stage the whole 64x64 Q and K tiles (transposed: [k][m]) in one pass
    #pragma unroll
    for (int q = 0; q < 4; ++q) {
        const int kb = lk + 4*q;
        const float4 qr = *(const float4*)(Qre + (size_t)(bm+lm)*512 + h*64 + kb);
        const float4 qi = *(const float4*)(Qim + (size_t)(bm+lm)*512 + h*64 + kb);
        const float4 kr = *(const float4*)(Kre + (size_t)(bn+lm)*512 + h*64 + kb);
        const float4 ki = *(const float4*)(Kim + (size_t)(bn+lm)*512 + h*64 + kb);
        Qs_re[kb+0][lm]=qr.x; Qs_re[kb+1][lm]=qr.y; Qs_re[kb+2][lm]=qr.z; Qs_re[kb+3][lm]=qr.w;
        Qs_im[kb+0][lm]=qi.x; Qs_im[kb+1][lm]=qi.y; Qs_im[kb+2][lm]=qi.z; Qs_im[kb+3][lm]=qi.w;
        Ks_re[kb+0][lm]=kr.x; Ks_re[kb+1][lm]=kr.y; Ks_re[kb+2][lm]=kr.z; Ks_re[kb+3][lm]=kr.w;
        Ks_im[kb+0][lm]=ki.x; Ks_im[kb+1][lm]=ki.y; Ks_im[kb+2][lm]=ki.z; Ks_im[kb+3][lm]=ki.w;
    }
    if (tid < 64) rs[tid] = 0.f;
    __syncthreads();
    float dr[4][4] = {{0.f}}, di[4][4] = {{0.f}};
    #pragma unroll
    for (int k = 0; k < 64; ++k) {
        const float4 xr = *(const float4*)&Qs_re[k][tm];
        const float4 xi = *(const float4*)&Qs_im[k][tm];
        const float4 yr = *(const float4*)&Ks_re[k][tn];
        const float4 yi = *(const float4*)&Ks_im[k][tn];
        const float axr[4] = {xr.x, xr.y, xr.z, xr.w};
        const float axi[4] = {xi.x, xi.y, xi.z, xi.w};
        const float byr[4] = {yr.x, yr.y, yr.z, yr.w};
        const float byi[4] = {yi.x, yi.y, yi.z, yi.w};
        #pragma unroll
        for (int i = 0; i < 4; ++i) {
            #pragma unroll
            for (int j = 0; j < 4; ++j) {
                dr[i][j] += axr[i]*byr[j] + axi[i]*byi[j];   // re(conj(q)*k)
                di[i][j] += axr[i]*byi[j] - axi[i]*byr[j];   // im(conj(q)*k)
            }
        }
    }
    float rpart[4] = {0.f, 0.f, 0.f, 0.f};
    #pragma unroll
    for (int i = 0; i < 4; ++i) {
        #pragma unroll
        for (int j = 0; j < 4; ++j) {
            const float b2v = (dr[i][j]*dr[i][j] + di[i][j]*di[i][j]) * 0.015625f;
            B2[(size_t)h*1048576 + (size_t)(bm+tm+i)*1024 + (bn+tn+j)] = b2v;
            rpart[i] += b2v;
        }
    }
    #pragma unroll
    for (int i = 0; i < 4; ++i) atomicAdd(&rs[tm+i], rpart[i]);
    __syncthreads();
    if (tid < 64) atomicAdd(&RS[h*1024 + bm + tid], rs[tid]);
}

// Per (h,n) row: exact top-102 radix select, softmax, weighted V gather.
__launch_bounds__(256)
__global__ void select_kernel(const float* __restrict__ B2, const float* __restrict__ RS,
                              const float* __restrict__ Vre, const float* __restrict__ Vim,
                              float* __restrict__ AOre, float* __restrict__ AOim)
{
    __shared__ float sv[1024];
    __shared__ unsigned int hist[256];
    __shared__ int ssum[256];
    __shared__ unsigned int sc[4];
    __shared__ float sel_v[104];
    __shared__ int sel_i[104];
    __shared__ float sel_w[104];
    __shared__ float rbuf[256];
    const int bid = blockIdx.x;
    const int h = bid >> 10, n = bid & 1023;
    const int tid = threadIdx.x;
    const float* row = B2 + (size_t)h * 1048576 + (size_t)n * 1024;
    #pragma unroll
    for (int e = 0; e < 4; ++e) sv[tid + 256*e] = row[tid + 256*e];
    if (tid == 0) sc[2] = 0u;
    __syncthreads();

    unsigned prefix = 0u, pmask = 0u;
    int krem = KTOP;
    for (int pass = 0; pass < 4; ++pass) {
        const int shift = 24 - 8 * pass;
        hist[tid] = 0u;
        __syncthreads();
        #pragma unroll
        for (int e = 0; e < 4; ++e) {
            const unsigned u = __float_as_uint(sv[tid + 256*e]);
            if ((u & pmask) == prefix) atomicAdd(&hist[(u >> shift) & 255u], 1u);
        }
        __syncthreads();
        ssum[tid] = (int)hist[tid];
        __syncthreads();
        for (int off = 1; off < 256; off <<= 1) {
            const int add = (tid + off < 256) ? ssum[tid + off] : 0;
            __syncthreads();
            ssum[tid] += add;
            __syncthreads();
        }
        const int above = (tid < 255) ? ssum[tid + 1] : 0;
        if (ssum[tid] >= krem && above < krem) {
            sc[0] = (unsigned)tid;
            sc[1] = (unsigned)(krem - above);
        }
        __syncthreads();
        prefix |= sc[0] << shift;
        pmask |= 0xFFu << shift;
        krem = (int)sc[1];
        __syncthreads();
    }
    const unsigned T = prefix;
    const int m = krem;   // ties at T: lowest indices first (jax top_k order)

    #pragma unroll
    for (int e = 0; e < 4; ++e) {
        const int i = tid + 256*e;
        const float v = sv[i];
        const unsigned u = __float_as_uint(v);
        bool sel = (u > T);
        if (!sel && u == T) {
            int rank = 0;
            for (int j = 0; j < i; ++j) rank += (__float_as_uint(sv[j]) == T) ? 1 : 0;
            sel = (rank < m);
        }
        if (sel) {
            const unsigned p = atomicAdd(&sc[2], 1u);
            if (p < 104u) { sel_v[p] = v; sel_i[p] = i; }
        }
    }
    __syncthreads();

    rbuf[tid] = (tid < KTOP) ? sel_v[tid] : 0.f;
    __syncthreads();
    for (int st = 128; st > 0; st >>= 1) { if (tid < st) rbuf[tid] += rbuf[tid + st]; __syncthreads(); }
    const float sumtop = rbuf[0];
    __syncthreads();
    rbuf[tid] = (tid < KTOP) ? sel_v[tid] : -1.f;
    __syncthreads();
    for (int st = 128; st > 0; st >>= 1) { if (tid < st) rbuf[tid] = fmaxf(rbuf[tid], rbuf[tid + st]); __syncthreads(); }
    const float vmax = rbuf[0];
    __syncthreads();

    const float S_row = RS[(h << 10) + n];
    const float denom = sumtop + 1e-8f * S_row;    // == (sum tp + 1e-8) * S_row
    const float scl = (float)KTOP / denom;
    if (tid < KTOP) sel_w[tid] = expf(sel_v[tid] * scl - vmax * scl);
    __syncthreads();
    rbuf[tid] = (tid < KTOP) ? sel_w[tid] : 0.f;
    __syncthreads();
    for (int st = 128; st > 0; st >>= 1) { if (tid < st) rbuf[tid] += rbuf[tid + st]; __syncthreads(); }
    const float Z = rbuf[0];
    __syncthreads();

    if (tid < 128) {
        const int d = tid & 63;
        const int im = tid >> 6;
        const float* Vp = im ? Vim : Vre;
        const int base = h * 64 + d;
        float acc = 0.f;
        for (int j = 0; j < KTOP; ++j) acc += sel_w[j] * Vp[(size_t)sel_i[j] * 512 + base];
        acc /= Z;
        float* AOp = im ? AOim : AOre;
        AOp[(size_t)n * 512 + h * 64 + d] = acc;
    }
}

// ---------------------------------------------------------------------------
extern "C" void kernel_launch(void* const* d_in, const int* in_sizes, int n_in,
                              void* d_out, int out_size, void* d_ws, size_t ws_size,
                              hipStream_t stream)
{
    (void)in_sizes; (void)n_in; (void)d_ws; (void)ws_size;
    const float* x_re = (const float*)d_in[0];
    const float* x_im = (const float*)d_in[1];
    // d_in[10..13] (phase MLP) are dead code.

    float* pool = nullptr;
    hipGetSymbolAddress((void**)&pool, HIP_SYMBOL(g_pool));   // query only; capture-safe

    float* Wall = pool;                // 4 complex 512^2: [W0re|W0im|W1re|...]
    float* RSg  = Wall + 4*CMAT;       // 8192 row sums (8 heads x 1024)
    float* R    = RSg + 8192;          // union region
    // Phase A (all 4 weights batched): 6 buffers x 4 weights x CMAT
    float* A  = R;
    float* S  = R + 4*CMAT;
    float* S2 = R + 8*CMAT;
    float* X  = R + 12*CMAT;           // U, then NS ping
    float* X2 = R + 16*CMAT;           // X0, then NS pong
    float* T  = R + 20*CMAT;           // NS temp
    // Phase B (overlays the same region):
    float* Q  = R;                     // CPROJ floats each
    float* Kp = R + CPROJ;
    float* V  = R + 2*CPROJ;
    float* AO = R + 3*CPROJ;
    float* B2 = R + 4*CPROJ;           // 8 x 1024x1024

    const int aoff = (int)(A - pool);

    // ---- Phase A: Cayley unitaries, all 4 weights per dispatch (z=4) ----
    build_A_kernel<<<dim3(1024,4),256,0,stream>>>(
        (const float*)d_in[2],(const float*)d_in[3],(const float*)d_in[4],(const float*)d_in[5],
        (const float*)d_in[6],(const float*)d_in[7],(const float*)d_in[8],(const float*)d_in[9], aoff);
    // S = A*A   (mode 0)
    cgemm_kernel<<<dim3(8,16,4),256,0,stream>>>(A,A+PLANE,CMAT, A,A+PLANE,CMAT,
                                                A,A+PLANE,CMAT, A,nullptr,CMAT,
                                                S,S+PLANE,CMAT, 512,512,512, 0.f, 0, 0);
    // S2 = S*S; U = 5.5 S + 0.5 S2 -> X slot  (mode 2, D=S, Ewr=X)
    cgemm_kernel<<<dim3(8,16,4),256,0,stream>>>(S,S+PLANE,CMAT, S,S+PLANE,CMAT,
                                                S,S+PLANE,CMAT, S,X,CMAT,
                                                S2,S2+PLANE,CMAT, 512,512,512, 0.f, 2, 0);
    // X0 = (60.5 I + 48 S + 23 S2 + S2*U)/61.5 -> X2  (mode 3, D=S, E=S2)
    cgemm_kernel<<<dim3(8,16,4),256,0,stream>>>(S2,S2+PLANE,CMAT, X,X+PLANE,CMAT,
                                                S,S+PLANE,CMAT, S2,nullptr,CMAT,
                                                X2,X2+PLANE,CMAT, 512,512,512, 0.f, 3, 0);
    // 2 Newton-Schulz iterations: X <- X(2I - B X), B = I - S
    float* Xc = X2; float* Xn = X;     // X0 lives in X2; X slot (U) is dead
    for (int it = 0; it < 2; ++it) {
        // T = 1*X - S*X  (mode 1)
        cgemm_kernel<<<dim3(8,16,4),256,0,stream>>>(S,S+PLANE,CMAT, Xc,Xc+PLANE,CMAT,
                                                    Xc,Xc+PLANE,CMAT, S,nullptr,CMAT,
                                                    T,T+PLANE,CMAT, 512,512,512, 1.f, 1, 0);
        // Xn = 2*X - X*T  (mode 1)
        cgemm_kernel<<<dim3(8,16,4),256,0,stream>>>(Xc,Xc+PLANE,CMAT, T,T+PLANE,CMAT,
                                                    Xc,Xc+PLANE,CMAT, S,nullptr,CMAT,
                                                    Xn,Xn+PLANE,CMAT, 512,512,512, 2.f, 1, 0);
        float* tmp = Xc; Xc = Xn; Xn = tmp;
    }
    // W = 2X + 2*A*X - I  (mode 4, D=X) -> Wall   [= (I-A)^{-1}(I+A)]
    cgemm_kernel<<<dim3(8,16,4),256,0,stream>>>(A,A+PLANE,CMAT, Xc,Xc+PLANE,CMAT,
                                                Xc,Xc+PLANE,CMAT, S,nullptr,CMAT,
                                                Wall,Wall+PLANE,CMAT, 512,512,512, 0.f, 4, 0);

    // ---- Phase B: projections Q,K,V = x @ W[0..2] (batched z=3, mode 0) ----
    cgemm_kernel<<<dim3(8,32,3),256,0,stream>>>(x_re,x_im,0, Wall,Wall+PLANE,CMAT,
                                                x_re,x_im,0, S,nullptr,0,
                                                Q,Q+PPLANE,CPROJ, 1024,512,512, 0.f, 0, 0);

    zero_kernel<<<32,256,0,stream>>>(RSg, 8192);
    scores_kernel<<<dim3(16,16,8),256,0,stream>>>(Q,Q+PPLANE, Kp,Kp+PPLANE, B2, RSg);
    select_kernel<<<8192,256,0,stream>>>(B2, RSg, V,V+PPLANE, AO,AO+PPLANE);

    // ---- Output projection straight to d_out (mode 5: bounded scalar) ----
    // z=2 row-halves via sA=sC=PLANE (row stride 512 floats); im plane
    // offset PPLANE is uniform; bnd = out_floats - b*PLANE inside.
    cgemm_kernel<<<dim3(8,16,2),256,0,stream>>>(AO,AO+PPLANE,PLANE, Wall+3*CMAT,Wall+3*CMAT+PLANE,0,
                                                AO,AO+PPLANE,0, S,nullptr,0,
                                                (float*)d_out,nullptr,PLANE, 512,512,512, 0.f, 5, out_size);
}

// Round 6
// 995.864 us; speedup vs baseline: 1.2037x; 1.0234x over previous
//
#include <hip/hip_runtime.h>
#include <math.h>

// ---------------------------------------------------------------------------
// QuantumSuperpositionAttention  (B=1, N=1024, DIM=512, H=8, DH=64, k=102)
//
// Identities:
//  * phase MLP is dead code: |alpha * e^{i phi}|^2 == |alpha|^2
//  * cayley(M): A = 0.02*((Mre - Mre^T) + i(Mim + Mim^T));
//    W = (I-A)^{-1}(I+A) = 2(I+A)X - I,  X = inv(I - A^2), spec [1,5).
//  * inv: deg-4 minimax init (PS form) + 2 quadratic NS -> rho ~ 7e-8.
//  * GEMM CORE LESSONS (R9..R18): the 32x64/2x4/BK=32 dbuf core at >=2
//    blocks/CU is the local optimum (~82us phase-A, ~123us QKV); LDS read
//    BW is the structural wall (VALUBusy ~56%, LDS-pipe oversubscribed
//    ~1.7x at 4 SIMDs/CU). 4x4 microtiles regress at low occupancy;
//    split-K+combine net loss; MFMA bf16-split priced out (small-N GEMM
//    efficiency ~300TF at this size => no win over fp32). DO NOT TOUCH.
//  * ERROR BUDGET (R6..R19 calibrated): W-chain realization changes at
//    fp32 floor (~1e-7) are SAFE (R18 split-K passed, absmax 0.00195).
//    Residual 4.3e-6 FAILED (R19). Baseline absmax 0.01025 = 94% of
//    threshold: top-k ties have NO slack. NS chain CLOSED at 8 GEMMs.
//  * ACCURACY RULES (R7/R9): never change float summation ORDER anywhere
//    in the Wq/Wk/Q/K/scores/select-weights/gather chain. Integer
//    restructures (radix scan) are bit-exact and free.
//  * denom = sumtop + 1e-8*S_row: S_row enters scaled by 1e-8 (sub-ulp of
//    denom). Historical RS was float-atomic (nondeterministic order) and
//    passed with stable absmax => S_row order provably insensitive.
//  * D_OUT BOUNDS RULE (R10/R11): every d_out store bounds-checked.
//
// R21 (on R20 base, 1019us PASS):
//  * select: shfl-based integer suffix scan (6 barriers/pass vs ~20);
//    computes S_row in-block via deterministic tree.
//  * scores: RS/atomic tail removed; zero_kernel dispatch removed.
//  * build_A: LDS-transpose tiles -> both M reads coalesced.
// ---------------------------------------------------------------------------

#define PLANE   262144      // 512*512
#define CMAT    524288      // floats per complex 512x512 (2 MB)
#define PPLANE  524288      // 1024*512
#define CPROJ   1048576     // floats per complex 1024x512 (4 MB)
#define KTOP    102

#define R_FLOATS 12582912
#define POOL_FLOATS (4*CMAT + 8192 + R_FLOATS)
__device__ __attribute__((aligned(256))) float g_pool[POOL_FLOATS];

// ---------------------------------------------------------------------------
// Complex planar GEMM, R16 core: 32x64 C-tile / 256 thr / 2x4 microtile /
// BK=32 / LDS double-buffer + reg prefetch. Grid (N/64, M/32, batch).
// Epilogue modes:
//  0: C = A*B
//  1: C = dcoef*D - A*B                       (NS steps)
//  2: C = A*B (=S2);  E = 5.5*D + 0.5*C      (D=S, E=U)
//  3: C = (60.5*I + 48*D + 23*E + A*B)/61.5  (D=S, E=S2; C=X0)
//  4: C = 2*D + 2*A*B - I                    (D=X; C=W)
//  5: C = A*B, scalar stores bounded by out_floats; im plane at +PPLANE
//     (bnd = out_floats - b*sC; global im index = b*sC + PPLANE + idx)
// ---------------------------------------------------------------------------
__launch_bounds__(256)
__global__ void cgemm_kernel(
    const float* __restrict__ Are, const float* __restrict__ Aim, int sA,
    const float* __restrict__ Bre, const float* __restrict__ Bim, int sB,
    const float* __restrict__ Dre, const float* __restrict__ Dim, int sD,
    const float* __restrict__ Ere2, float* __restrict__ Ewr, int sE,
    float* __restrict__ Cre, float* __restrict__ Cim, int sC,
    int M, int N, int Kd, float dcoef, int mode, int out_floats)
{
    __shared__ float As_re[2][32][34], As_im[2][32][34];
    __shared__ float Bs_re[2][32][68], Bs_im[2][32][68];
    const int b = blockIdx.z;
    Are += (size_t)b * sA; Aim += (size_t)b * sA;
    Bre += (size_t)b * sB; Bim += (size_t)b * sB;
    Dre += (size_t)b * sD; Dim += (size_t)b * sD;
    const float* Ere = Ere2 + (size_t)b * sE;
    const float* Eim = Ere + PLANE;      // E input (S2) planes
    float* Uwr = Ewr ? (Ewr + (size_t)b * sE) : (float*)0;
    Cre += (size_t)b * sC; Cim += (size_t)b * sC;
    const int bnd = mode == 5 ? (out_floats - b * sC) : 0;
    const int tid = threadIdx.x;
    const int bm = blockIdx.y * 32, bn = blockIdx.x * 64;
    const int tm = (tid >> 4) << 1;      // 0..30 (2 rows)
    const int tn = (tid & 15) << 2;      // 0..60 (4 cols)
    const int lmA = tid >> 3;            // 0..31
    const int lkA = (tid & 7) << 2;      // 0,4..28
    const int lkB = tid >> 4;            // 0..15
    const int lnB = (tid & 15) << 2;     // 0..60
    float cr[2][4] = {{0.f}}, ci[2][4] = {{0.f}};
    const float* pAre = Are + (size_t)(bm + lmA) * Kd + lkA;
    const float* pAim = Aim + (size_t)(bm + lmA) * Kd + lkA;
    const float* pBre = Bre + (size_t)lkB * N + bn + lnB;
    const float* pBim = Bim + (size_t)lkB * N + bn + lnB;
    // preload K-tile 0 into registers
    float4 ar  = *(const float4*)(pAre);
    float4 ai  = *(const float4*)(pAim);
    float4 br0 = *(const float4*)(pBre);
    float4 bi0 = *(const float4*)(pBim);
    float4 br1 = *(const float4*)(pBre + (size_t)16 * N);
    float4 bi1 = *(const float4*)(pBim + (size_t)16 * N);
    for (int k0 = 0; k0 < Kd; k0 += 32) {
        const int buf = (k0 >> 5) & 1;
        As_re[buf][lkA+0][lmA] = ar.x; As_re[buf][lkA+1][lmA] = ar.y;
        As_re[buf][lkA+2][lmA] = ar.z; As_re[buf][lkA+3][lmA] = ar.w;
        As_im[buf][lkA+0][lmA] = ai.x; As_im[buf][lkA+1][lmA] = ai.y;
        As_im[buf][lkA+2][lmA] = ai.z; As_im[buf][lkA+3][lmA] = ai.w;
        *(float4*)&Bs_re[buf][lkB][lnB] = br0;
        *(float4*)&Bs_im[buf][lkB][lnB] = bi0;
        *(float4*)&Bs_re[buf][lkB+16][lnB] = br1;
        *(float4*)&Bs_im[buf][lkB+16][lnB] = bi1;
        __syncthreads();
        // issue next tile's global loads; latency hides under compute below
        const int kn = k0 + 32;
        if (kn < Kd) {
            ar  = *(const float4*)(pAre + kn);
            ai  = *(const float4*)(pAim + kn);
            br0 = *(const float4*)(pBre + (size_t)kn * N);
            bi0 = *(const float4*)(pBim + (size_t)kn * N);
            br1 = *(const float4*)(pBre + (size_t)(kn + 16) * N);
            bi1 = *(const float4*)(pBim + (size_t)(kn + 16) * N);
        }
        #pragma unroll
        for (int k = 0; k < 32; ++k) {
            const float2 xr = *(const float2*)&As_re[buf][k][tm];
            const float2 xi = *(const float2*)&As_im[buf][k][tm];
            const float4 yr = *(const float4*)&Bs_re[buf][k][tn];
            const float4 yi = *(const float4*)&Bs_im[buf][k][tn];
            const float axr[2] = {xr.x, xr.y};
            const float axi[2] = {xi.x, xi.y};
            const float byr[4] = {yr.x, yr.y, yr.z, yr.w};
            const float byi[4] = {yi.x, yi.y, yi.z, yi.w};
            #pragma unroll
            for (int i = 0; i < 2; ++i) {
                #pragma unroll
                for (int j = 0; j < 4; ++j) {
                    cr[i][j] += axr[i]*byr[j] - axi[i]*byi[j];
                    ci[i][j] += axr[i]*byi[j] + axi[i]*byr[j];
                }
            }
        }
    }
    #pragma unroll
    for (int i = 0; i < 2; ++i) {
        const int row = bm + tm + i;
        const size_t idx = (size_t)row * N + bn + tn;
        float vr[4] = {cr[i][0], cr[i][1], cr[i][2], cr[i][3]};
        float vi[4] = {ci[i][0], ci[i][1], ci[i][2], ci[i][3]};
        if (mode == 1) {
            const float4 dr4 = *(const float4*)(Dre + idx);
            const float4 di4 = *(const float4*)(Dim + idx);
            const float dr[4] = {dr4.x, dr4.y, dr4.z, dr4.w};
            const float di[4] = {di4.x, di4.y, di4.z, di4.w};
            #pragma unroll
            for (int j = 0; j < 4; ++j) { vr[j] = dcoef*dr[j] - vr[j]; vi[j] = dcoef*di[j] - vi[j]; }
        } else if (mode == 2) {
            const float4 dr4 = *(const float4*)(Dre + idx);
            const float4 di4 = *(const float4*)(Dim + idx);
            const float dr[4] = {dr4.x, dr4.y, dr4.z, dr4.w};
            const float di[4] = {di4.x, di4.y, di4.z, di4.w};
            float ur[4], ui[4];
            #pragma unroll
            for (int j = 0; j < 4; ++j) { ur[j] = 5.5f*dr[j] + 0.5f*vr[j]; ui[j] = 5.5f*di[j] + 0.5f*vi[j]; }
            *(float4*)(Uwr + idx) = make_float4(ur[0], ur[1], ur[2], ur[3]);
            *(float4*)(Uwr + PLANE + idx) = make_float4(ui[0], ui[1], ui[2], ui[3]);
        } else if (mode == 3) {
            const float inv61 = 1.0f/61.5f;
            const float4 sr4 = *(const float4*)(Dre + idx);
            const float4 si4 = *(const float4*)(Dim + idx);
            const float4 s2r = *(const float4*)(Ere + idx);
            const float4 s2i = *(const float4*)(Eim + idx);
            const float sr[4] = {sr4.x, sr4.y, sr4.z, sr4.w};
            const float si[4] = {si4.x, si4.y, si4.z, si4.w};
            const float tr[4] = {s2r.x, s2r.y, s2r.z, s2r.w};
            const float ti[4] = {s2i.x, s2i.y, s2i.z, s2i.w};
            #pragma unroll
            for (int j = 0; j < 4; ++j) {
                const float diag = (row == bn + tn + j) ? 60.5f : 0.0f;
                vr[j] = (diag + 48.f*sr[j] + 23.f*tr[j] + vr[j]) * inv61;
                vi[j] = (       48.f*si[j] + 23.f*ti[j] + vi[j]) * inv61;
            }
        } else if (mode == 4) {
            const float4 dr4 = *(const float4*)(Dre + idx);
            const float4 di4 = *(const float4*)(Dim + idx);
            const float dr[4] = {dr4.x, dr4.y, dr4.z, dr4.w};
            const float di[4] = {di4.x, di4.y, di4.z, di4.w};
            #pragma unroll
            for (int j = 0; j < 4; ++j) {
                const float diag = (row == bn + tn + j) ? 1.0f : 0.0f;
                vr[j] = 2.f*dr[j] + 2.f*vr[j] - diag;
                vi[j] = 2.f*di[j] + 2.f*vi[j];
            }
        }
        if (mode == 5) {
            // bounded scalar stores straight to d_out (copy_out semantics)
            #pragma unroll
            for (int j = 0; j < 4; ++j) {
                const size_t ire = idx + j;
                const size_t iim = (size_t)PPLANE + idx + j;
                if (ire < (size_t)bnd) Cre[ire] = vr[j];
                if (iim < (size_t)bnd) Cre[iim] = vi[j];
            }
        } else {
            *(float4*)(Cre + idx) = make_float4(vr[0], vr[1], vr[2], vr[3]);
            *(float4*)(Cim + idx) = make_float4(vi[0], vi[1], vi[2], vi[3]);
        }
    }
}

// A = 0.02*((Mre - Mre^T) + i(Mim + Mim^T)) for all 4 weights.
// R21: 32x32 LDS-transpose tiles; both M reads coalesced. Same arithmetic.
// grid (16, 16, 4), 256 threads.
__launch_bounds__(256)
__global__ void build_A_kernel(const float* __restrict__ W0re, const float* __restrict__ W0im,
                               const float* __restrict__ W1re, const float* __restrict__ W1im,
                               const float* __restrict__ W2re, const float* __restrict__ W2im,
                               const float* __restrict__ W3re, const float* __restrict__ W3im,
                               int aoff)
{
    __shared__ float Tre[32][33], Tim[32][33];
    float* Aout = g_pool + aoff;
    const int w = blockIdx.z;
    const float* Mre; const float* Mim;
    if      (w == 0) { Mre = W0re; Mim = W0im; }
    else if (w == 1) { Mre = W1re; Mim = W1im; }
    else if (w == 2) { Mre = W2re; Mim = W2im; }
    else             { Mre = W3re; Mim = W3im; }
    float* Are = Aout + (size_t)w * CMAT;
    float* Aim = Are + PLANE;
    const int r = blockIdx.y * 32, c = blockIdx.x * 32;
    const int tx = threadIdx.x & 31, ty = threadIdx.x >> 5;   // 8 rows/pass
    // stage M tile (c..c+31 rows, r..r+31 cols) for the transpose term
    #pragma unroll
    for (int p = 0; p < 4; ++p) {
        const int rr = ty + 8*p;
        Tre[rr][tx] = Mre[(size_t)(c+rr)*512 + r + tx];
        Tim[rr][tx] = Mim[(size_t)(c+rr)*512 + r + tx];
    }
    __syncthreads();
    #pragma unroll
    for (int p = 0; p < 4; ++p) {
        const int rr = ty + 8*p;            // local row in A tile
        const int i = r + rr, j = c + tx;   // global (i,j)
        const size_t o = (size_t)i*512 + j;
        Are[o] = 0.02f * (Mre[o] - Tre[tx][rr]);   // Mre[j][i]
        Aim[o] = 0.02f * (Mim[o] + Tim[tx][rr]);   // Mim[j][i]
    }
}

// All heads: b2[h,n,s] = |conj(Q[n,h,:]) . K[s,h,:]|^2 * SCALE^2.
// R20 full-K staging; R21: RS/atomic tail removed (select computes S_row).
__launch_bounds__(256)
__global__ void scores_kernel(const float* __restrict__ Qre, const float* __restrict__ Qim,
                              const float* __restrict__ Kre, const float* __restrict__ Kim,
                              float* __restrict__ B2)
{
    __shared__ float Qs_re[64][68], Qs_im[64][68], Ks_re[64][68], Ks_im[64][68];
    const int h = blockIdx.z;
    const int bm = blockIdx.y * 64, bn = blockIdx.x * 64;
    const int tid = threadIdx.x;
    const int tm = (tid >> 4) << 2, tn = (tid & 15) << 2;
    const int lm = tid >> 2;            // 0..63 (tile row)
    const int lk = (tid & 3) << 4;      // 0,16,32,48 (k-chunk base)
    #pragma unroll
    for (int q = 0; q < 4; ++q) {
        const int kb = lk + 4*q;
        const float4 qr = *(const float4*)(Qre + (size_t)(bm+lm)*512 + h*64 + kb);
        const float4 qi = *(const float4*)(Qim + (size_t)(bm+lm)*512 + h*64 + kb);
        const float4 kr = *(const float4*)(Kre + (size_t)(bn+lm)*512 + h*64 + kb);
        const float4 ki = *(const float4*)(Kim + (size_t)(bn+lm)*512 + h*64 + kb);
        Qs_re[kb+0][lm]=qr.x; Qs_re[kb+1][lm]=qr.y; Qs_re[kb+2][lm]=qr.z; Qs_re[kb+3][lm]=qr.w;
        Qs_im[kb+0][lm]=qi.x; Qs_im[kb+1][lm]=qi.y; Qs_im[kb+2][lm]=qi.z; Qs_im[kb+3][lm]=qi.w;
        Ks_re[kb+0][lm]=kr.x; Ks_re[kb+1][lm]=kr.y; Ks_re[kb+2][lm]=kr.z; Ks_re[kb+3][lm]=kr.w;
        Ks_im[kb+0][lm]=ki.x; Ks_im[kb+1][lm]=ki.y; Ks_im[kb+2][lm]=ki.z; Ks_im[kb+3][lm]=ki.w;
    }
    __syncthreads();
    float dr[4][4] = {{0.f}}, di[4][4] = {{0.f}};
    #pragma unroll
    for (int k = 0; k < 64; ++k) {
        const float4 xr = *(const float4*)&Qs_re[k][tm];
        const float4 xi = *(const float4*)&Qs_im[k][tm];
        const float4 yr = *(const float4*)&Ks_re[k][tn];
        const float4 yi = *(const float4*)&Ks_im[k][tn];
        const float axr[4] = {xr.x, xr.y, xr.z, xr.w};
        const float axi[4] = {xi.x, xi.y, xi.z, xi.w};
        const float byr[4] = {yr.x, yr.y, yr.z, yr.w};
        const float byi[4] = {yi.x, yi.y, yi.z, yi.w};
        #pragma unroll
        for (int i = 0; i < 4; ++i) {
            #pragma unroll
            for (int j = 0; j < 4; ++j) {
                dr[i][j] += axr[i]*byr[j] + axi[i]*byi[j];   // re(conj(q)*k)
                di[i][j] += axr[i]*byi[j] - axi[i]*byr[j];   // im(conj(q)*k)
            }
        }
    }
    #pragma unroll
    for (int i = 0; i < 4; ++i) {
        #pragma unroll
        for (int j = 0; j < 4; ++j) {
            const float b2v = (dr[i][j]*dr[i][j] + di[i][j]*di[i][j]) * 0.015625f;
            B2[(size_t)h*1048576 + (size_t)(bm+tm+i)*1024 + (bn+tn+j)] = b2v;
        }
    }
}

// Per (h,n) row: exact top-102 radix select, softmax, weighted V gather.
// R21: shfl-based integer suffix scan; in-block S_row (1e-8-scaled term).
__launch_bounds__(256)
__global__ void select_kernel(const float* __restrict__ B2,
                              const float* __restrict__ Vre, const float* __restrict__ Vim,
                              float* __restrict__ AOre, float* __restrict__ AOim)
{
    __shared__ float sv[1024];
    __shared__ unsigned int hist[256];
    __shared__ int ssum[256];
    __shared__ int wtot[4];
    __shared__ unsigned int sc[4];
    __shared__ float sel_v[104];
    __shared__ int sel_i[104];
    __shared__ float sel_w[104];
    __shared__ float rbuf[256];
    __shared__ float srow_sh;
    const int bid = blockIdx.x;
    const int h = bid >> 10, n = bid & 1023;
    const int tid = threadIdx.x;
    const float* row = B2 + (size_t)h * 1048576 + (size_t)n * 1024;
    #pragma unroll
    for (int e = 0; e < 4; ++e) sv[tid + 256*e] = row[tid + 256*e];
    if (tid == 0) sc[2] = 0u;
    __syncthreads();

    // S_row = sum of the full row (deterministic tree). Enters denom only
    // as 1e-8*S_row (sub-ulp of denom) -> order-insensitive, proven by the
    // historical float-atomic RS passing with stable absmax.
    rbuf[tid] = sv[tid] + sv[tid+256] + sv[tid+512] + sv[tid+768];
    __syncthreads();
    for (int st = 128; st > 0; st >>= 1) { if (tid < st) rbuf[tid] += rbuf[tid + st]; __syncthreads(); }
    if (tid == 0) srow_sh = rbuf[0];
    __syncthreads();

    const int lane = tid & 63, wv = tid >> 6;
    unsigned prefix = 0u, pmask = 0u;
    int krem = KTOP;
    for (int pass = 0; pass < 4; ++pass) {
        const int shift = 24 - 8 * pass;
        hist[tid] = 0u;
        __syncthreads();
        #pragma unroll
        for (int e = 0; e < 4; ++e) {
            const unsigned u = __float_as_uint(sv[tid + 256*e]);
            if ((u & pmask) == prefix) atomicAdd(&hist[(u >> shift) & 255u], 1u);
        }
        __syncthreads();
        // integer suffix scan: ssum[t] = sum_{t'>=t} hist[t'] (bit-exact)
        int v = (int)hist[tid];
        #pragma unroll
        for (int off = 1; off < 64; off <<= 1) {
            const int o = __shfl_down(v, off);
            if (lane + off < 64) v += o;
        }
        if (lane == 0) wtot[wv] = v;           // wave totals (lane 0 = full)
        __syncthreads();
        int addv = 0;
        for (int w2 = wv + 1; w2 < 4; ++w2) addv += wtot[w2];
        ssum[tid] = v + addv;
        __syncthreads();
        const int above = (tid < 255) ? ssum[tid + 1] : 0;
        if (ssum[tid] >= krem && above < krem) {
            sc[0] = (unsigned)tid;
            sc[1] = (unsigned)(krem - above);
        }
        __syncthreads();
        prefix |= sc[0] << shift;
        pmask |= 0xFFu << shift;
        krem = (int)sc[1];
        __syncthreads();
    }
    const unsigned T = prefix;
    const int m = krem;   // ties at T: lowest indices first (jax top_k order)

    #pragma unroll
    for (int e = 0; e < 4; ++e) {
        const int i = tid + 256*e;
        const float v = sv[i];
        const unsigned u = __float_as_uint(v);
        bool sel = (u > T);
        if (!sel && u == T) {
            int rank = 0;
            for (int j = 0; j < i; ++j) rank += (__float_as_uint(sv[j]) == T) ? 1 : 0;
            sel = (rank < m);
        }
        if (sel) {
            const unsigned p = atomicAdd(&sc[2], 1u);
            if (p < 104u) { sel_v[p] = v; sel_i[p] = i; }
        }
    }
    __syncthreads();

    rbuf[tid] = (tid < KTOP) ? sel_v[tid] : 0.f;
    __syncthreads();
    for (int st = 128; st > 0; st >>= 1) { if (tid < st) rbuf[tid] += rbuf[tid + st]; __syncthreads(); }
    const float sumtop = rbuf[0];
    __syncthreads();
    rbuf[tid] = (tid < KTOP) ? sel_v[tid] : -1.f;
    __syncthreads();
    for (int st = 128; st > 0; st >>= 1) { if (tid < st) rbuf[tid] = fmaxf(rbuf[tid], rbuf[tid + st]); __syncthreads(); }
    const float vmax = rbuf[0];
    __syncthreads();

    const float denom = sumtop + 1e-8f * srow_sh;  // == (sum tp + 1e-8) * S_row
    const float scl = (float)KTOP / denom;
    if (tid < KTOP) sel_w[tid] = expf(sel_v[tid] * scl - vmax * scl);
    __syncthreads();
    rbuf[tid] = (tid < KTOP) ? sel_w[tid] : 0.f;
    __syncthreads();
    for (int st = 128; st > 0; st >>= 1) { if (tid < st) rbuf[tid] += rbuf[tid + st]; __syncthreads(); }
    const float Z = rbuf[0];
    __syncthreads();

    if (tid < 128) {
        const int d = tid & 63;
        const int im = tid >> 6;
        const float* Vp = im ? Vim : Vre;
        const int base = h * 64 + d;
        float acc = 0.f;
        for (int j = 0; j < KTOP; ++j) acc += sel_w[j] * Vp[(size_t)sel_i[j] * 512 + base];
        acc /= Z;
        float* AOp = im ? AOim : AOre;
        AOp[(size_t)n * 512 + h * 64 + d] = acc;
    }
}

// ---------------------------------------------------------------------------
extern "C" void kernel_launch(void* const* d_in, const int* in_sizes, int n_in,
                              void* d_out, int out_size, void* d_ws, size_t ws_size,
                              hipStream_t stream)
{
    (void)in_sizes; (void)n_in; (void)d_ws; (void)ws_size;
    const float* x_re = (const float*)d_in[0];
    const float* x_im = (const float*)d_in[1];
    // d_in[10..13] (phase MLP) are dead code.

    float* pool = nullptr;
    hipGetSymbolAddress((void**)&pool, HIP_SYMBOL(g_pool));   // query only; capture-safe

    float* Wall = pool;                // 4 complex 512^2: [W0re|W0im|W1re|...]
    float* R    = Wall + 4*CMAT + 8192;   // union region (8192 pad legacy)
    // Phase A (all 4 weights batched): 6 buffers x 4 weights x CMAT
    float* A  = R;
    float* S  = R + 4*CMAT;
    float* S2 = R + 8*CMAT;
    float* X  = R + 12*CMAT;           // U, then NS ping
    float* X2 = R + 16*CMAT;           // X0, then NS pong
    float* T  = R + 20*CMAT;           // NS temp
    // Phase B (overlays the same region):
    float* Q  = R;                     // CPROJ floats each
    float* Kp = R + CPROJ;
    float* V  = R + 2*CPROJ;
    float* AO = R + 3*CPROJ;
    float* B2 = R + 4*CPROJ;           // 8 x 1024x1024

    const int aoff = (int)(A - pool);

    // ---- Phase A: Cayley unitaries, all 4 weights per dispatch ----
    build_A_kernel<<<dim3(16,16,4),256,0,stream>>>(
        (const float*)d_in[2],(const float*)d_in[3],(const float*)d_in[4],(const float*)d_in[5],
        (const float*)d_in[6],(const float*)d_in[7],(const float*)d_in[8],(const float*)d_in[9], aoff);
    // S = A*A   (mode 0)
    cgemm_kernel<<<dim3(8,16,4),256,0,stream>>>(A,A+PLANE,CMAT, A,A+PLANE,CMAT,
                                                A,A+PLANE,CMAT, A,nullptr,CMAT,
                                                S,S+PLANE,CMAT, 512,512,512, 0.f, 0, 0);
    // S2 = S*S; U = 5.5 S + 0.5 S2 -> X slot  (mode 2, D=S, Ewr=X)
    cgemm_kernel<<<dim3(8,16,4),256,0,stream>>>(S,S+PLANE,CMAT, S,S+PLANE,CMAT,
                                                S,S+PLANE,CMAT, S,X,CMAT,
                                                S2,S2+PLANE,CMAT, 512,512,512, 0.f, 2, 0);
    // X0 = (60.5 I + 48 S + 23 S2 + S2*U)/61.5 -> X2  (mode 3, D=S, E=S2)
    cgemm_kernel<<<dim3(8,16,4),256,0,stream>>>(S2,S2+PLANE,CMAT, X,X+PLANE,CMAT,
                                                S,S+PLANE,CMAT, S2,nullptr,CMAT,
                                                X2,X2+PLANE,CMAT, 512,512,512, 0.f, 3, 0);
    // 2 Newton-Schulz iterations: X <- X(2I - B X), B = I - S
    float* Xc = X2; float* Xn = X;     // X0 lives in X2; X slot (U) is dead
    for (int it = 0; it < 2; ++it) {
        // T = 1*X - S*X  (mode 1)
        cgemm_kernel<<<dim3(8,16,4),256,0,stream>>>(S,S+PLANE,CMAT, Xc,Xc+PLANE,CMAT,
                                                    Xc,Xc+PLANE,CMAT, S,nullptr,CMAT,
                                                    T,T+PLANE,CMAT, 512,512,512, 1.f, 1, 0);
        // Xn = 2*X - X*T  (mode 1)
        cgemm_kernel<<<dim3(8,16,4),256,0,stream>>>(Xc,Xc+PLANE,CMAT, T,T+PLANE,CMAT,
                                                    Xc,Xc+PLANE,CMAT, S,nullptr,CMAT,
                                                    Xn,Xn+PLANE,CMAT, 512,512,512, 2.f, 1, 0);
        float* tmp = Xc; Xc = Xn; Xn = tmp;
    }
    // W = 2X + 2*A*X - I  (mode 4, D=X) -> Wall   [= (I-A)^{-1}(I+A)]
    cgemm_kernel<<<dim3(8,16,4),256,0,stream>>>(A,A+PLANE,CMAT, Xc,Xc+PLANE,CMAT,
                                                Xc,Xc+PLANE,CMAT, S,nullptr,CMAT,
                                                Wall,Wall+PLANE,CMAT, 512,512,512, 0.f, 4, 0);

    // ---- Phase B: projections Q,K,V = x @ W[0..2] (batched z=3, mode 0) ----
    cgemm_kernel<<<dim3(8,32,3),256,0,stream>>>(x_re,x_im,0, Wall,Wall+PLANE,CMAT,
                                                x_re,x_im,0, S,nullptr,0,
                                                Q,Q+PPLANE,CPROJ, 1024,512,512, 0.f, 0, 0);

    scores_kernel<<<dim3(16,16,8),256,0,stream>>>(Q,Q+PPLANE, Kp,Kp+PPLANE, B2);
    select_kernel<<<8192,256,0,stream>>>(B2, V,V+PPLANE, AO,AO+PPLANE);

    // ---- Output projection straight to d_out (mode 5: bounded scalar) ----
    // z=2 row-halves via sA=sC=PLANE (row stride 512 floats); im plane
    // offset PPLANE is uniform; bnd = out_floats - b*PLANE inside.
    cgemm_kernel<<<dim3(8,16,2),256,0,stream>>>(AO,AO+PPLANE,PLANE, Wall+3*CMAT,Wall+3*CMAT+PLANE,0,
                                                AO,AO+PPLANE,0, S,nullptr,0,
                                                (float*)d_out,nullptr,PLANE, 512,512,512, 0.f, 5, out_size);
}